// Round 1
// baseline (716.488 us; speedup 1.0000x reference)
//
#include <hip/hip_runtime.h>
#include <math.h>

// Problem constants (from reference): N=100000 nodes, E=6400000 edges.
// out[n] = [cos(theta_n), sin(theta_n), w_n],
//   w_n = S_y / max(||S||, eps) where S = sum over edges e with dst==n of
//         (cos(x[src_e]-theta[n]), sin(x[src_e]-theta[n])).
// (The reference's /cnt mean cancels inside the L2-normalize.)

#define EPS 1e-12f

__global__ void zero_kernel(float* __restrict__ p, int n) {
    int i = blockIdx.x * blockDim.x + threadIdx.x;
    if (i < n) p[i] = 0.0f;
}

__global__ void edge_kernel(const float* __restrict__ x,
                            const float* __restrict__ theta,
                            const int* __restrict__ esrc,
                            const int* __restrict__ edst,
                            float* __restrict__ acc,   // [N*2] interleaved (cos,sin)
                            int E) {
    int i = blockIdx.x * blockDim.x + threadIdx.x;
    if (i >= E) return;
    int s = esrc[i];
    int d = edst[i];
    float dt = x[s] - theta[d];
    float sn, cs;
    __sincosf(dt, &sn, &cs);
    atomicAdd(&acc[2 * d],     cs);
    atomicAdd(&acc[2 * d + 1], sn);
}

__global__ void node_kernel(const float* __restrict__ theta,
                            const float* __restrict__ acc,
                            float* __restrict__ out,   // [N*3]
                            int N) {
    int n = blockIdx.x * blockDim.x + threadIdx.x;
    if (n >= N) return;
    float t = theta[n];
    float sn, cs;
    __sincosf(t, &sn, &cs);
    float sx = acc[2 * n];
    float sy = acc[2 * n + 1];
    float nrm = fmaxf(sqrtf(sx * sx + sy * sy), EPS);
    out[3 * n + 0] = cs;
    out[3 * n + 1] = sn;
    out[3 * n + 2] = sy / nrm;
}

extern "C" void kernel_launch(void* const* d_in, const int* in_sizes, int n_in,
                              void* d_out, int out_size, void* d_ws, size_t ws_size,
                              hipStream_t stream) {
    const float* x     = (const float*)d_in[0];
    const float* theta = (const float*)d_in[1];
    const int*   esrc  = (const int*)d_in[2];   // harness delivers integer inputs as int32
    const int*   edst  = (const int*)d_in[3];
    float*       out   = (float*)d_out;
    float*       acc   = (float*)d_ws;          // N*2 floats = 800 KB scratch

    int N = in_sizes[0];
    int E = in_sizes[2];

    const int B = 256;
    // 1) zero accumulator (ws is re-poisoned to 0xAA before every timed call)
    zero_kernel<<<(2 * N + B - 1) / B, B, 0, stream>>>(acc, 2 * N);
    // 2) per-edge scatter-accumulate
    edge_kernel<<<(E + B - 1) / B, B, 0, stream>>>(x, theta, esrc, edst, acc, E);
    // 3) per-node epilogue
    node_kernel<<<(N + B - 1) / B, B, 0, stream>>>(theta, acc, out, N);
}

// Round 2
// 266.455 us; speedup vs baseline: 2.6890x; 2.6890x over previous
//
#include <hip/hip_runtime.h>
#include <math.h>

// N=100000 nodes, E=6400000 edges, avg degree 64.
// out[n] = [cos(th_n), sin(th_n), w_n],  w_n = S_y / max(||S||, eps),
//   S_x = cos(th)*C + sin(th)*S,  S_y = cos(th)*S - sin(th)*C,
//   C_n = sum_{e:dst=n} cos(x[src_e]),  S_n = sum_{e:dst=n} sin(x[src_e]),
//   ||(S_x,S_y)|| = ||(C,S)||  (rotation preserves norm).
// Strategy: per-edge global atomics (R1: 634us, 400MB of 32B write-through
// atomic transactions) replaced by LDS-privatized node-partition histogram.

#define EPS 1e-12f
#define NPART 16       // node partitions; R = ceil(N/NPART) = 6250 -> 50KB LDS
#define NSLICE 32      // edge slices per partition; grid = NPART*NSLICE = 512
#define RMAX 6250
#define BLK 512

// ---------------- fast path ----------------

__global__ void build_cs_kernel(const float* __restrict__ x,
                                float2* __restrict__ cst, int N) {
    int i = blockIdx.x * blockDim.x + threadIdx.x;
    if (i < N) {
        float sn, cs;
        __sincosf(x[i], &sn, &cs);
        cst[i] = make_float2(cs, sn);
    }
}

__global__ __launch_bounds__(BLK) void scatter_lds_kernel(
        const float2* __restrict__ cst,
        const int* __restrict__ esrc,
        const int* __restrict__ edst,
        float* __restrict__ buf,       // [NPART*NSLICE][2*R]: [C(R)|S(R)] per block
        int E, int R) {
    __shared__ float lacc[2 * RMAX];   // SoA: [0,R)=C, [R,2R)=S -> full bank spread
    const int p = blockIdx.x / NSLICE;
    const int s = blockIdx.x % NSLICE;
    const int pBeg = p * R;

    for (int k = threadIdx.x; k < 2 * R; k += BLK) lacc[k] = 0.0f;
    __syncthreads();

    const int per = (E + NSLICE - 1) / NSLICE;
    const int beg = s * per;
    const int end = min(beg + per, E);

    if ((beg & 3) == 0) {
        const int nvec = (end - beg) & ~3;
        const int endv = beg + nvec;
        for (int i = beg + threadIdx.x * 4; i < endv; i += BLK * 4) {
            int4 d4 = *(const int4*)&edst[i];
            {   unsigned dl = (unsigned)(d4.x - pBeg);
                if (dl < (unsigned)R) { float2 v = cst[esrc[i + 0]];
                    atomicAdd(&lacc[dl], v.x); atomicAdd(&lacc[R + dl], v.y); } }
            {   unsigned dl = (unsigned)(d4.y - pBeg);
                if (dl < (unsigned)R) { float2 v = cst[esrc[i + 1]];
                    atomicAdd(&lacc[dl], v.x); atomicAdd(&lacc[R + dl], v.y); } }
            {   unsigned dl = (unsigned)(d4.z - pBeg);
                if (dl < (unsigned)R) { float2 v = cst[esrc[i + 2]];
                    atomicAdd(&lacc[dl], v.x); atomicAdd(&lacc[R + dl], v.y); } }
            {   unsigned dl = (unsigned)(d4.w - pBeg);
                if (dl < (unsigned)R) { float2 v = cst[esrc[i + 3]];
                    atomicAdd(&lacc[dl], v.x); atomicAdd(&lacc[R + dl], v.y); } }
        }
        for (int i = endv + threadIdx.x; i < end; i += BLK) {
            unsigned dl = (unsigned)(edst[i] - pBeg);
            if (dl < (unsigned)R) { float2 v = cst[esrc[i]];
                atomicAdd(&lacc[dl], v.x); atomicAdd(&lacc[R + dl], v.y); }
        }
    } else {
        for (int i = beg + threadIdx.x; i < end; i += BLK) {
            unsigned dl = (unsigned)(edst[i] - pBeg);
            if (dl < (unsigned)R) { float2 v = cst[esrc[i]];
                atomicAdd(&lacc[dl], v.x); atomicAdd(&lacc[R + dl], v.y); }
        }
    }

    __syncthreads();
    float* dst = buf + (size_t)blockIdx.x * (2 * R);
    for (int k = threadIdx.x; k < 2 * R; k += BLK) dst[k] = lacc[k];
}

__global__ void reduce_node_kernel(const float* __restrict__ theta,
                                   const float* __restrict__ buf,
                                   float* __restrict__ out, int N, int R) {
    int n = blockIdx.x * blockDim.x + threadIdx.x;
    if (n >= N) return;
    int p = n / R, j = n - p * R;
    float C = 0.0f, Sv = 0.0f;
    size_t base = (size_t)p * NSLICE * 2 * R + j;
    #pragma unroll 8
    for (int s = 0; s < NSLICE; ++s) {
        const float* b = buf + base + (size_t)s * 2 * R;
        C  += b[0];
        Sv += b[R];
    }
    float sn, cs;
    __sincosf(theta[n], &sn, &cs);
    float nrm = fmaxf(sqrtf(C * C + Sv * Sv), EPS);
    out[3 * n + 0] = cs;
    out[3 * n + 1] = sn;
    out[3 * n + 2] = (cs * Sv - sn * C) / nrm;
}

// ---------------- fallback path (R1: global atomics) ----------------

__global__ void zero_kernel(float* __restrict__ p, int n) {
    int i = blockIdx.x * blockDim.x + threadIdx.x;
    if (i < n) p[i] = 0.0f;
}

__global__ void edge_atomic_kernel(const float* __restrict__ x,
                                   const float* __restrict__ theta,
                                   const int* __restrict__ esrc,
                                   const int* __restrict__ edst,
                                   float* __restrict__ acc, int E) {
    int i = blockIdx.x * blockDim.x + threadIdx.x;
    if (i >= E) return;
    int s = esrc[i], d = edst[i];
    float dt = x[s] - theta[d];
    float sn, cs;
    __sincosf(dt, &sn, &cs);
    atomicAdd(&acc[2 * d], cs);
    atomicAdd(&acc[2 * d + 1], sn);
}

__global__ void node_atomic_kernel(const float* __restrict__ theta,
                                   const float* __restrict__ acc,
                                   float* __restrict__ out, int N) {
    int n = blockIdx.x * blockDim.x + threadIdx.x;
    if (n >= N) return;
    float sn, cs;
    __sincosf(theta[n], &sn, &cs);
    float sx = acc[2 * n], sy = acc[2 * n + 1];
    float nrm = fmaxf(sqrtf(sx * sx + sy * sy), EPS);
    out[3 * n + 0] = cs;
    out[3 * n + 1] = sn;
    out[3 * n + 2] = sy / nrm;
}

extern "C" void kernel_launch(void* const* d_in, const int* in_sizes, int n_in,
                              void* d_out, int out_size, void* d_ws, size_t ws_size,
                              hipStream_t stream) {
    const float* x     = (const float*)d_in[0];
    const float* theta = (const float*)d_in[1];
    const int*   esrc  = (const int*)d_in[2];
    const int*   edst  = (const int*)d_in[3];
    float*       out   = (float*)d_out;

    int N = in_sizes[0];
    int E = in_sizes[2];
    int R = (N + NPART - 1) / NPART;

    size_t buf_bytes = (size_t)NPART * NSLICE * 2 * R * sizeof(float);
    size_t cst_bytes = (size_t)N * sizeof(float2);

    if (R <= RMAX && ws_size >= buf_bytes + cst_bytes) {
        float*  buf = (float*)d_ws;
        float2* cst = (float2*)((char*)d_ws + buf_bytes);
        build_cs_kernel<<<(N + 255) / 256, 256, 0, stream>>>(x, cst, N);
        scatter_lds_kernel<<<NPART * NSLICE, BLK, 0, stream>>>(cst, esrc, edst, buf, E, R);
        reduce_node_kernel<<<(N + 255) / 256, 256, 0, stream>>>(theta, buf, out, N, R);
    } else {
        float* acc = (float*)d_ws;
        const int B = 256;
        zero_kernel<<<(2 * N + B - 1) / B, B, 0, stream>>>(acc, 2 * N);
        edge_atomic_kernel<<<(E + B - 1) / B, B, 0, stream>>>(x, theta, esrc, edst, acc, E);
        node_atomic_kernel<<<(N + B - 1) / B, B, 0, stream>>>(theta, acc, out, N);
    }
}